// Round 11
// baseline (101.151 us; speedup 1.0000x reference)
//
#include <hip/hip_runtime.h>
#include <hip/hip_bf16.h>
#include <math.h>

#define B_ 4096
#define F_ 64
#define A_ 8
#define U_ 32

typedef float f32x4 __attribute__((ext_vector_type(4)));
typedef short bf16x8 __attribute__((ext_vector_type(8)));

// ws layout:
//   [0, 4 MB): frag blob, per (a,j) 8192 B, index (a*64+j):
//     [0,4096):  K frags, fragid = kc*2+ut, 64 lanes x 16 B:
//                bf16 K[f = kc*32 + q*8 + i][u = ut*16 + c]
//     [4096,8192): W frags, fragid = ft, u-PERMUTED to the Z^T slot order:
//                slot i of lane (q,c): bf16 exp(2*K[f = ft*16 + c][u = pi(q,i)]),
//                pi(q,i) = (i<4) ? 4q+i : 16 + 4q + (i-4)
//   [4 MB, 4 MB + 64 KB): Kd fp32 (bf16-rounded): [a*64+j][32] = K[j,a][j][u]
#define KD_OFF (4ull << 20)

static __device__ __forceinline__ unsigned int pk_bf16(float lo, float hi) {
    union { __hip_bfloat162 h2; unsigned int u; } cv;
    cv.h2 = __float22bfloat162_rn(make_float2(lo, hi));
    return cv.u;
}
// round fp32 -> bf16 -> fp32 (match what the MFMA actually sees)
static __device__ __forceinline__ float rb(float f) {
    unsigned int u = __float_as_uint(f);
    u += 0x7FFFu + ((u >> 16) & 1u);
    return __uint_as_float(u & 0xFFFF0000u);
}
// bf16 bit-pattern of the rounded value / back
static __device__ __forceinline__ unsigned short fbits(float f) {
    unsigned int u = __float_as_uint(f);
    u += 0x7FFFu + ((u >> 16) & 1u);
    return (unsigned short)(u >> 16);
}
static __device__ __forceinline__ float b2f(unsigned short h) {
    return __uint_as_float((unsigned int)h << 16);
}

// ---------------- prep: one block per (a,j); stage 8 KB, emit frags + Kd ----------------
__global__ __launch_bounds__(256) void ife_prep(const float* __restrict__ kern,
                                                unsigned char* __restrict__ ws)
{
    const int bid = blockIdx.x;           // a*64 + j
    const int a = bid >> 6, j = bid & 63;
    const int t = threadIdx.x;
    __shared__ float st[64][36];          // [f][u], pitch 36 (16B-aligned float4 slots)

    const float* src = kern + ((size_t)j * A_ + a) * (F_ * U_);
    {
        const int f = t >> 2, u0 = (t & 3) * 8;
        *(float4*)&st[f][u0]     = *(const float4*)&src[f * U_ + u0];
        *(float4*)&st[f][u0 + 4] = *(const float4*)&src[f * U_ + u0 + 4];
    }
    __syncthreads();

    unsigned char* dst = ws + (size_t)bid * 8192;
    const int fragid = t >> 6, lane = t & 63, q = lane >> 4, c = lane & 15;

    // K frag (fragid = kc*2 + ut)
    {
        const int kc = fragid >> 1, ut = fragid & 1;
        const int f0 = kc * 32 + q * 8, u = ut * 16 + c;
        unsigned int w[4];
        #pragma unroll
        for (int i = 0; i < 4; ++i)
            w[i] = pk_bf16(st[f0 + 2 * i][u], st[f0 + 2 * i + 1][u]);
        *(uint4*)(dst + fragid * 1024 + lane * 16) = make_uint4(w[0], w[1], w[2], w[3]);
    }
    // W frag (fragid = ft), u-permuted: slots = {4q..4q+3, 16+4q..16+4q+3}
    {
        const int f = fragid * 16 + c;
        const float4 wa = *(const float4*)&st[f][q * 4];        // u = 4q .. 4q+3
        const float4 wb = *(const float4*)&st[f][16 + q * 4];   // u = 16+4q .. 16+4q+3
        unsigned int w[4];
        w[0] = pk_bf16(__expf(2.f * wa.x), __expf(2.f * wa.y));
        w[1] = pk_bf16(__expf(2.f * wa.z), __expf(2.f * wa.w));
        w[2] = pk_bf16(__expf(2.f * wb.x), __expf(2.f * wb.y));
        w[3] = pk_bf16(__expf(2.f * wb.z), __expf(2.f * wb.w));
        *(uint4*)(dst + 4096 + fragid * 1024 + lane * 16) = make_uint4(w[0], w[1], w[2], w[3]);
    }
    // Kd (bf16-rounded so the rank-1 correction exactly cancels the MFMA j-term)
    if (t < U_)
        ((float*)(ws + KD_OFF))[(size_t)bid * U_ + t] = rb(st[j][t]);
}

// ---------------- main: (a, 64-row tile); 8 waves = 2 row-halves x 4 j-groups ------------
// R10 accounting: the floor is redundant operand bytes — each 8 KB (K,W) tile was read by
// 4 waves from LDS (2 MB/block). Here each wave computes 32 rows (2 row-blocks) for 16 j's,
// so each tile is read by only 2 waves: LDS frag traffic halves (1 MB/block), barriers
// 32 -> 16. Xf/Kd stored as bf16 bits (lossless: values are bf16-rounded) so the 64 KB
// staging double-buffer still fits 2 blocks/CU (76.3 KB total).
__global__ __launch_bounds__(512, 4) void ife_main(const float* __restrict__ x,
                                                   const unsigned char* __restrict__ ws,
                                                   float* __restrict__ out)
{
    const int a = blockIdx.y, bt = blockIdx.x, t = threadIdx.x;
    const int wv = t >> 6, lane = t & 63, q = lane >> 4, c = lane & 15;
    const int jg = wv >> 1, rh = wv & 1;   // j-group (4), row-half (2)

    __shared__ __align__(16) unsigned short Xf_h[64 * 66];   // bf16 X tile (8.4 KB)
    __shared__ __align__(16) unsigned short Kd_h[64 * 32];   // bf16 Kd (4 KB)
    __shared__ __align__(16) unsigned char Fbuf[2][4][8192]; // frag dbuf, 4 tiles (64 KB)

    // X frags for BOTH row-blocks of this wave's half (B operand of Z^T)
    bf16x8 Xh[2][2];
    #pragma unroll
    for (int rb_ = 0; rb_ < 2; ++rb_) {
        const float* xr = x + (size_t)(bt * 64 + rh * 32 + rb_ * 16 + c) * F_;
        #pragma unroll
        for (int kc = 0; kc < 2; ++kc) {
            const float4 va = *(const float4*)&xr[kc * 32 + q * 8];
            const float4 vb = *(const float4*)&xr[kc * 32 + q * 8 + 4];
            union { unsigned int u[4]; bf16x8 v; } H;
            H.u[0] = pk_bf16(va.x, va.y);
            H.u[1] = pk_bf16(va.z, va.w);
            H.u[2] = pk_bf16(vb.x, vb.y);
            H.u[3] = pk_bf16(vb.z, vb.w);
            Xh[rb_][kc] = H.v;
        }
    }
    // Xf_h staging (bf16 bits of rounded X); 512 threads x 8 scalars
    {
        const int row = t >> 3, cb = (t & 7) * 8;
        const float* xsrc = x + (size_t)(bt * 64 + row) * F_ + cb;
        const float4 v0 = *(const float4*)&xsrc[0];
        const float4 v1 = *(const float4*)&xsrc[4];
        unsigned short* xd = &Xf_h[row * 66 + cb];
        xd[0] = fbits(v0.x); xd[1] = fbits(v0.y); xd[2] = fbits(v0.z); xd[3] = fbits(v0.w);
        xd[4] = fbits(v1.x); xd[5] = fbits(v1.y); xd[6] = fbits(v1.z); xd[7] = fbits(v1.w);
    }
    // Kd_h staging (values already bf16-rounded; store the bf16 bits)
    {
        const float* kd = (const float*)(ws + KD_OFF) + (size_t)a * 64 * U_;
        const int jj = t >> 3, u0 = (t & 7) * 4;
        const float4 v = *(const float4*)&kd[jj * U_ + u0];
        ushort4 us;
        us.x = (unsigned short)(__float_as_uint(v.x) >> 16);
        us.y = (unsigned short)(__float_as_uint(v.y) >> 16);
        us.z = (unsigned short)(__float_as_uint(v.z) >> 16);
        us.w = (unsigned short)(__float_as_uint(v.w) >> 16);
        *(ushort4*)&Kd_h[jj * 32 + u0] = us;
    }

    const unsigned char* blob = ws + (size_t)a * 64 * 8192;
    const f32x4 vzero = (f32x4){0.f, 0.f, 0.f, 0.f};

    union { unsigned int u[4]; bf16x8 v; } oc;
    oc.u[0] = 0x3F803F80u; oc.u[1] = 0x3F803F80u; oc.u[2] = 0x3F803F80u; oc.u[3] = 0x3F803F80u;
    const bf16x8 ONES = oc.v;

    f32x4 S[2][4];   // [row-block][ft]: score[row][f = ft*16 + 4q + r]
    #pragma unroll
    for (int rb_ = 0; rb_ < 2; ++rb_) {
        S[rb_][0] = vzero; S[rb_][1] = vzero; S[rb_][2] = vzero; S[rb_][3] = vzero;
    }

    // stage step s: 4 tiles (j = tg*16+s), wave wv covers tile wv>>1, half wv&1 (4 KB)
    typedef const __attribute__((address_space(1))) unsigned int gau32;
    typedef __attribute__((address_space(3))) unsigned int lau32;
    auto STAGE = [&](int buf, int s) {
        const int tile = wv >> 1, half = wv & 1;
        const int jt = tile * 16 + s;
        const unsigned char* g = blob + (size_t)jt * 8192 + half * 4096 + lane * 16;
        unsigned char* l = &Fbuf[buf][tile][half * 4096];
        __builtin_amdgcn_global_load_lds((gau32*)(g),        (lau32*)(l),        16, 0, 0);
        __builtin_amdgcn_global_load_lds((gau32*)(g + 1024), (lau32*)(l + 1024), 16, 0, 0);
        __builtin_amdgcn_global_load_lds((gau32*)(g + 2048), (lau32*)(l + 2048), 16, 0, 0);
        __builtin_amdgcn_global_load_lds((gau32*)(g + 3072), (lau32*)(l + 3072), 16, 0, 0);
    };

    STAGE(0, 0);
    __syncthreads();   // Xf/Kd stores + first tiles complete

    int cur = 0;
    #pragma unroll 1
    for (int s = 0; s < 16; ++s) {
        if (s < 15) STAGE(cur ^ 1, s + 1);       // async; hides under this step's compute

        const unsigned char* pt = &Fbuf[cur][jg][lane * 16];
        const int j = jg * 16 + s;

        // K frags (ds_read_b128 x4)
        const bf16x8 K0 = *(const bf16x8*)(pt);
        const bf16x8 K1 = *(const bf16x8*)(pt + 1024);
        const bf16x8 K2 = *(const bf16x8*)(pt + 2048);
        const bf16x8 K3 = *(const bf16x8*)(pt + 3072);

        // per-j scalars
        const ushort4 ka = *(const ushort4*)&Kd_h[j * 32 + q * 4];        // u = 4q+r
        const ushort4 kb = *(const ushort4*)&Kd_h[j * 32 + 16 + q * 4];   // u = 16+4q+r
        const float xj0 = b2f(Xf_h[(rh * 32 + c) * 66 + j]);
        const float xj1 = b2f(Xf_h[(rh * 32 + 16 + c) * 66 + j]);
        f32x4 kda, kdb;
        kda[0] = b2f(ka.x); kda[1] = b2f(ka.y); kda[2] = b2f(ka.z); kda[3] = b2f(ka.w);
        kdb[0] = b2f(kb.x); kdb[1] = b2f(kb.y); kdb[2] = b2f(kb.z); kdb[3] = b2f(kb.w);

        // Z^T for both row-blocks: lane (q,c): ZA -> u=4q+r, ZB -> u=16+4q+r, col=row c
        f32x4 ZA0 = vzero, ZB0 = vzero, ZA1 = vzero, ZB1 = vzero;
        ZA0 = __builtin_amdgcn_mfma_f32_16x16x32_bf16(K0, Xh[0][0], ZA0, 0, 0, 0);
        ZA0 = __builtin_amdgcn_mfma_f32_16x16x32_bf16(K2, Xh[0][1], ZA0, 0, 0, 0);
        ZB0 = __builtin_amdgcn_mfma_f32_16x16x32_bf16(K1, Xh[0][0], ZB0, 0, 0, 0);
        ZB0 = __builtin_amdgcn_mfma_f32_16x16x32_bf16(K3, Xh[0][1], ZB0, 0, 0, 0);
        ZA1 = __builtin_amdgcn_mfma_f32_16x16x32_bf16(K0, Xh[1][0], ZA1, 0, 0, 0);
        ZA1 = __builtin_amdgcn_mfma_f32_16x16x32_bf16(K2, Xh[1][1], ZA1, 0, 0, 0);
        ZB1 = __builtin_amdgcn_mfma_f32_16x16x32_bf16(K1, Xh[1][0], ZB1, 0, 0, 0);
        ZB1 = __builtin_amdgcn_mfma_f32_16x16x32_bf16(K3, Xh[1][1], ZB1, 0, 0, 0);

        // W frags
        const bf16x8 W0 = *(const bf16x8*)(pt + 4096);
        const bf16x8 W1 = *(const bf16x8*)(pt + 5120);
        const bf16x8 W2 = *(const bf16x8*)(pt + 6144);
        const bf16x8 W3 = *(const bf16x8*)(pt + 7168);

        // row-block 0: exp + pack + denominator-MFMA + PV
        {
            union { unsigned int u[4]; bf16x8 v; } E;
            E.u[0] = pk_bf16(__expf(ZA0[0] - xj0 * kda[0]), __expf(ZA0[1] - xj0 * kda[1]));
            E.u[1] = pk_bf16(__expf(ZA0[2] - xj0 * kda[2]), __expf(ZA0[3] - xj0 * kda[3]));
            E.u[2] = pk_bf16(__expf(ZB0[0] - xj0 * kdb[0]), __expf(ZB0[1] - xj0 * kdb[1]));
            E.u[3] = pk_bf16(__expf(ZB0[2] - xj0 * kdb[2]), __expf(ZB0[3] - xj0 * kdb[3]));
            const f32x4 sv = __builtin_amdgcn_mfma_f32_16x16x32_bf16(ONES, E.v, vzero, 0, 0, 0);
            const f32x4 D0 = __builtin_amdgcn_mfma_f32_16x16x32_bf16(W0, E.v, vzero, 0, 0, 0);
            const f32x4 D1 = __builtin_amdgcn_mfma_f32_16x16x32_bf16(W1, E.v, vzero, 0, 0, 0);
            const f32x4 D2 = __builtin_amdgcn_mfma_f32_16x16x32_bf16(W2, E.v, vzero, 0, 0, 0);
            const f32x4 D3 = __builtin_amdgcn_mfma_f32_16x16x32_bf16(W3, E.v, vzero, 0, 0, 0);
            const float inv = __builtin_amdgcn_rcpf(sv[0]);
            #pragma unroll
            for (int r = 0; r < 4; ++r) {
                S[0][0][r] += D0[r] * inv;
                S[0][1][r] += D1[r] * inv;
                S[0][2][r] += D2[r] * inv;
                S[0][3][r] += D3[r] * inv;
            }
        }
        // row-block 1
        {
            union { unsigned int u[4]; bf16x8 v; } E;
            E.u[0] = pk_bf16(__expf(ZA1[0] - xj1 * kda[0]), __expf(ZA1[1] - xj1 * kda[1]));
            E.u[1] = pk_bf16(__expf(ZA1[2] - xj1 * kda[2]), __expf(ZA1[3] - xj1 * kda[3]));
            E.u[2] = pk_bf16(__expf(ZB1[0] - xj1 * kdb[0]), __expf(ZB1[1] - xj1 * kdb[1]));
            E.u[3] = pk_bf16(__expf(ZB1[2] - xj1 * kdb[2]), __expf(ZB1[3] - xj1 * kdb[3]));
            const f32x4 sv = __builtin_amdgcn_mfma_f32_16x16x32_bf16(ONES, E.v, vzero, 0, 0, 0);
            const f32x4 D0 = __builtin_amdgcn_mfma_f32_16x16x32_bf16(W0, E.v, vzero, 0, 0, 0);
            const f32x4 D1 = __builtin_amdgcn_mfma_f32_16x16x32_bf16(W1, E.v, vzero, 0, 0, 0);
            const f32x4 D2 = __builtin_amdgcn_mfma_f32_16x16x32_bf16(W2, E.v, vzero, 0, 0, 0);
            const f32x4 D3 = __builtin_amdgcn_mfma_f32_16x16x32_bf16(W3, E.v, vzero, 0, 0, 0);
            const float inv = __builtin_amdgcn_rcpf(sv[0]);
            #pragma unroll
            for (int r = 0; r < 4; ++r) {
                S[1][0][r] += D0[r] * inv;
                S[1][1][r] += D1[r] * inv;
                S[1][2][r] += D2[r] * inv;
                S[1][3][r] += D3[r] * inv;
            }
        }

        __syncthreads();   // staging for s+1 complete + all reads of cur done
        cur ^= 1;
    }

    // ---- reduce partial S across the 4 j-groups through LDS (reuse Fbuf: 64 KB) ----
    float* Sred = (float*)Fbuf;                 // [wave][lane][32 floats]
    {
        float* pp = Sred + ((size_t)wv * 64 + lane) * 32;
        #pragma unroll
        for (int rb_ = 0; rb_ < 2; ++rb_)
            #pragma unroll
            for (int ft = 0; ft < 4; ++ft)
                *(f32x4*)(pp + rb_ * 16 + ft * 4) = S[rb_][ft];
    }
    __syncthreads();
    if (jg == 0) {
        f32x4 F[2][4];
        #pragma unroll
        for (int rb_ = 0; rb_ < 2; ++rb_) {
            F[rb_][0] = vzero; F[rb_][1] = vzero; F[rb_][2] = vzero; F[rb_][3] = vzero;
        }
        #pragma unroll
        for (int g = 0; g < 4; ++g) {
            const float* pp = Sred + ((size_t)(g * 2 + rh) * 64 + lane) * 32;
            #pragma unroll
            for (int rb_ = 0; rb_ < 2; ++rb_)
                #pragma unroll
                for (int ft = 0; ft < 4; ++ft)
                    F[rb_][ft] += *(const f32x4*)(pp + rb_ * 16 + ft * 4);
        }

        // epilogue: mean over j, softmax over f. Lane (q,c): row's f = ft*16 + 4q + r.
        const float sc = 1.f / 64.f;
        #pragma unroll
        for (int rb_ = 0; rb_ < 2; ++rb_) {
            float ex[4][4];
            float part = 0.f;
            #pragma unroll
            for (int r = 0; r < 4; ++r) {
                ex[0][r] = __expf(F[rb_][0][r] * sc);
                ex[1][r] = __expf(F[rb_][1][r] * sc);
                ex[2][r] = __expf(F[rb_][2][r] * sc);
                ex[3][r] = __expf(F[rb_][3][r] * sc);
                part += ex[0][r] + ex[1][r] + ex[2][r] + ex[3][r];
            }
            part += __shfl_xor(part, 16, 64);
            part += __shfl_xor(part, 32, 64);
            const float inv = 1.f / part;

            const int b = bt * 64 + rh * 32 + rb_ * 16 + c;
            float* o = out + ((size_t)a * B_ + b) * F_;
            #pragma unroll
            for (int ft = 0; ft < 4; ++ft) {
                float4 v;
                v.x = ex[ft][0] * inv;
                v.y = ex[ft][1] * inv;
                v.z = ex[ft][2] * inv;
                v.w = ex[ft][3] * inv;
                *(float4*)&o[ft * 16 + q * 4] = v;
            }
        }
    }
}

extern "C" void kernel_launch(void* const* d_in, const int* in_sizes, int n_in,
                              void* d_out, int out_size, void* d_ws, size_t ws_size,
                              hipStream_t stream) {
    (void)in_sizes; (void)n_in; (void)out_size; (void)ws_size;
    const float* x    = (const float*)d_in[0];   // [B, F]
    const float* kern = (const float*)d_in[1];   // [F, A, F, U]
    float* out        = (float*)d_out;           // [A, B, F]
    unsigned char* ws = (unsigned char*)d_ws;    // ~4.1 MB used

    hipLaunchKernelGGL(ife_prep, dim3(F_ * A_), dim3(256), 0, stream, kern, ws);
    hipLaunchKernelGGL(ife_main, dim3(B_ / 64, A_), dim3(512), 0, stream, x, ws, out);
}